// Round 1
// baseline (308.274 us; speedup 1.0000x reference)
//
#include <hip/hip_runtime.h>

// MHA: B=2, S=2048, D=1024, H=16, DK=DV=64
// out = softmax(mask(|QK^T/8|)) V, then output projection.
// All matmuls in bf16 MFMA (16x16x32), fp32 accumulate.

#define DI __device__ __forceinline__

typedef __bf16 bf16x8 __attribute__((ext_vector_type(8)));
typedef float f32x4 __attribute__((ext_vector_type(4)));
typedef unsigned short u16x8 __attribute__((ext_vector_type(8)));
typedef unsigned short u16x4 __attribute__((ext_vector_type(4)));

union U8 { u16x8 u; bf16x8 b; };

DI unsigned short f2bf(float f) {            // round-to-nearest-even
  unsigned int u = __float_as_uint(f);
  u += 0x7FFFu + ((u >> 16) & 1u);
  return (unsigned short)(u >> 16);
}

// ---------------- kernel 0a: x fp32 -> bf16 ----------------
__global__ __launch_bounds__(256) void k_conv_x(const float* __restrict__ x,
                                                unsigned short* __restrict__ xb) {
  size_t i = ((size_t)blockIdx.x * 256 + threadIdx.x) * 4;
  float4 v = *(const float4*)(x + i);
  u16x4 o;
  o[0] = f2bf(v.x); o[1] = f2bf(v.y); o[2] = f2bf(v.z); o[3] = f2bf(v.w);
  *(u16x4*)(xb + i) = o;
}

// ---------------- kernel 0b: W[k][n] f32 -> Wt[n][k] bf16 (1024x1024) ----------------
__global__ __launch_bounds__(256) void k_transpose(
    const float* __restrict__ W0, const float* __restrict__ W1,
    const float* __restrict__ W2, const float* __restrict__ W3,
    unsigned short* __restrict__ T0, unsigned short* __restrict__ T1,
    unsigned short* __restrict__ T2, unsigned short* __restrict__ T3) {
  const int z = blockIdx.z;
  const float* W = (z == 0) ? W0 : (z == 1) ? W1 : (z == 2) ? W2 : W3;
  unsigned short* T = (z == 0) ? T0 : (z == 1) ? T1 : (z == 2) ? T2 : T3;
  __shared__ unsigned short buf[32][33];
  const int k0 = blockIdx.x * 32, n0 = blockIdx.y * 32;
  const int tx = threadIdx.x, ty = threadIdx.y;   // (32, 8)
#pragma unroll
  for (int j = 0; j < 4; ++j) {
    int r = ty + j * 8;
    buf[r][tx] = f2bf(W[(size_t)(k0 + r) * 1024 + n0 + tx]);
  }
  __syncthreads();
#pragma unroll
  for (int j = 0; j < 4; ++j) {
    int c = ty + j * 8;
    T[(size_t)(n0 + c) * 1024 + k0 + tx] = buf[tx][c];
  }
}

// ---------------- shared GEMM main loop ----------------
// C(128x128) = A(128xK) * Wt(128xK)^T, K=1024, bf16 MFMA 16x16x32.
// A row-major [M][1024] bf16; Bm row-major [N][1024] bf16 (pre-transposed weight).
// LDS stride 40 elems (80B = 5*16B): ds_read_b128-aligned, 2-way banks (free).
#define LDK 40

DI void gemm_main(const unsigned short* __restrict__ A,
                  const unsigned short* __restrict__ Bm,
                  unsigned short* As, unsigned short* Bs,
                  int m0, int n0, f32x4 acc[4][4]) {
  const int tid = threadIdx.x;
  const int lane = tid & 63, wid = tid >> 6;
  const int wr = wid >> 1, wc = wid & 1;
  const int g = lane >> 4, lq = lane & 15;
  const int srow = tid >> 2, sq = tid & 3;

  for (int k0 = 0; k0 < 1024; k0 += 32) {
    __syncthreads();
#pragma unroll
    for (int j = 0; j < 2; ++j) {
      int r = srow + j * 64;
      *(u16x8*)&As[r * LDK + sq * 8] =
          *(const u16x8*)&A[(size_t)(m0 + r) * 1024 + k0 + sq * 8];
      *(u16x8*)&Bs[r * LDK + sq * 8] =
          *(const u16x8*)&Bm[(size_t)(n0 + r) * 1024 + k0 + sq * 8];
    }
    __syncthreads();
    U8 af[4], bfr[4];
#pragma unroll
    for (int f = 0; f < 4; ++f) {
      af[f].u  = *(const u16x8*)&As[(wr * 64 + f * 16 + lq) * LDK + g * 8];
      bfr[f].u = *(const u16x8*)&Bs[(wc * 64 + f * 16 + lq) * LDK + g * 8];
    }
#pragma unroll
    for (int i = 0; i < 4; ++i)
#pragma unroll
      for (int j = 0; j < 4; ++j)
        acc[i][j] = __builtin_amdgcn_mfma_f32_16x16x32_bf16(af[i].b, bfr[j].b,
                                                            acc[i][j], 0, 0, 0);
  }
}

// ---------------- kernel 1: QKV projection ----------------
// z=0: Q -> (B*H, S, 64); z=1: K -> (B*H, S, 64); z=2: V -> (B*H, 64, S) transposed
__global__ __launch_bounds__(256) void k_gemm_qkv(
    const unsigned short* __restrict__ xb,
    const unsigned short* __restrict__ Wqt, const unsigned short* __restrict__ Wkt,
    const unsigned short* __restrict__ Wvt,
    const float* __restrict__ bq, const float* __restrict__ bk,
    const float* __restrict__ bv,
    unsigned short* __restrict__ Qo, unsigned short* __restrict__ Ko,
    unsigned short* __restrict__ Vto) {
  __shared__ unsigned short As[128 * LDK];
  __shared__ unsigned short Bs[128 * LDK];
  const int z = blockIdx.z;
  const unsigned short* Bm = (z == 0) ? Wqt : (z == 1) ? Wkt : Wvt;
  const float* bias = (z == 0) ? bq : (z == 1) ? bk : bv;

  f32x4 acc[4][4];
#pragma unroll
  for (int i = 0; i < 4; ++i)
#pragma unroll
    for (int j = 0; j < 4; ++j) acc[i][j] = f32x4{0.f, 0.f, 0.f, 0.f};

  const int m0 = blockIdx.x * 128, n0 = blockIdx.y * 128;
  gemm_main(xb, Bm, As, Bs, m0, n0, acc);

  const int lane = threadIdx.x & 63, wid = threadIdx.x >> 6;
  const int wr = wid >> 1, wc = wid & 1;
  const int g = lane >> 4, lq = lane & 15;
  unsigned short* dstQK = (z == 0) ? Qo : Ko;
#pragma unroll
  for (int j = 0; j < 4; ++j) {
    int col = n0 + wc * 64 + j * 16 + lq;
    float bv_ = bias[col];
    int h = col >> 6, d = col & 63;
#pragma unroll
    for (int i = 0; i < 4; ++i) {
#pragma unroll
      for (int r = 0; r < 4; ++r) {
        int row = m0 + wr * 64 + i * 16 + g * 4 + r;
        int b = row >> 11, s = row & 2047;
        unsigned short hv = f2bf(acc[i][j][r] + bv_);
        if (z < 2)
          dstQK[(((size_t)(b * 16 + h)) * 2048 + s) * 64 + d] = hv;
        else
          Vto[(((size_t)(b * 16 + h)) * 64 + d) * 2048 + s] = hv;
      }
    }
  }
}

// ---------------- kernel 3: output projection (fp32 out + bias) ----------------
__global__ __launch_bounds__(256) void k_gemm_out(
    const unsigned short* __restrict__ Ob, const unsigned short* __restrict__ Wot,
    const float* __restrict__ bo, float* __restrict__ out) {
  __shared__ unsigned short As[128 * LDK];
  __shared__ unsigned short Bs[128 * LDK];
  f32x4 acc[4][4];
#pragma unroll
  for (int i = 0; i < 4; ++i)
#pragma unroll
    for (int j = 0; j < 4; ++j) acc[i][j] = f32x4{0.f, 0.f, 0.f, 0.f};

  const int m0 = blockIdx.x * 128, n0 = blockIdx.y * 128;
  gemm_main(Ob, Wot, As, Bs, m0, n0, acc);

  const int lane = threadIdx.x & 63, wid = threadIdx.x >> 6;
  const int wr = wid >> 1, wc = wid & 1;
  const int g = lane >> 4, lq = lane & 15;
#pragma unroll
  for (int j = 0; j < 4; ++j) {
    int col = n0 + wc * 64 + j * 16 + lq;
    float bv_ = bo[col];
#pragma unroll
    for (int i = 0; i < 4; ++i)
#pragma unroll
      for (int r = 0; r < 4; ++r) {
        int row = m0 + wr * 64 + i * 16 + g * 4 + r;
        out[(size_t)row * 1024 + col] = acc[i][j][r] + bv_;
      }
  }
}

// ---------------- kernel 2: flash attention with |scores| + causal ----------------
// grid (32 qtiles, 16 h, 2 b), block 256 (4 waves, 16 q-rows each).
// Q,K: (B*H, 2048, 64) bf16; Vt: (B*H, 64, 2048) bf16; O: (B, 2048, 1024) bf16.
__global__ __launch_bounds__(256) void k_flash(
    const unsigned short* __restrict__ Q, const unsigned short* __restrict__ Km,
    const unsigned short* __restrict__ Vt, unsigned short* __restrict__ O) {
  const int tid = threadIdx.x;
  const int lane = tid & 63, wid = tid >> 6;
  const int g = lane >> 4, lq = lane & 15;
  const int qt = blockIdx.x, h = blockIdx.y, b = blockIdx.z;
  const int bh = b * 16 + h;
  const int q0 = qt * 64;
  const size_t qkbase = (size_t)bh * 2048 * 64;
  const size_t vbase = (size_t)bh * 64 * 2048;

  __shared__ unsigned short P_lds[4 * 16 * 72];
  unsigned short* Pw = &P_lds[wid * 16 * 72];

  U8 aq0, aq1;
  {
    const unsigned short* qp = &Q[qkbase + (size_t)(q0 + wid * 16 + lq) * 64 + g * 8];
    aq0.u = *(const u16x8*)qp;
    aq1.u = *(const u16x8*)(qp + 32);
  }
  float m[4], l[4];
  f32x4 oacc[4];
#pragma unroll
  for (int r = 0; r < 4; ++r) { m[r] = -1e30f; l[r] = 0.f; }
#pragma unroll
  for (int c = 0; c < 4; ++c) oacc[c] = f32x4{0.f, 0.f, 0.f, 0.f};

  const int nt = qt + 1;
  for (int t = 0; t < nt; ++t) {
    const int kk0 = t * 64;
    // ---- QK^T (16 q x 64 k), A=Q rows, B=K rows (k-contig both)
    f32x4 sacc[4];
#pragma unroll
    for (int c = 0; c < 4; ++c) sacc[c] = f32x4{0.f, 0.f, 0.f, 0.f};
#pragma unroll
    for (int c = 0; c < 4; ++c) {
      const unsigned short* kp = &Km[qkbase + (size_t)(kk0 + c * 16 + lq) * 64 + g * 8];
      U8 b0, b1;
      b0.u = *(const u16x8*)kp;
      b1.u = *(const u16x8*)(kp + 32);
      sacc[c] = __builtin_amdgcn_mfma_f32_16x16x32_bf16(aq0.b, b0.b, sacc[c], 0, 0, 0);
      sacc[c] = __builtin_amdgcn_mfma_f32_16x16x32_bf16(aq1.b, b1.b, sacc[c], 0, 0, 0);
    }
    // ---- abs + causal mask + online softmax (rows live in 16-lane groups)
    float val[4][4];
#pragma unroll
    for (int c = 0; c < 4; ++c) {
      int col = kk0 + c * 16 + lq;
#pragma unroll
      for (int r = 0; r < 4; ++r) {
        int row = q0 + wid * 16 + g * 4 + r;
        float sv = fabsf(sacc[c][r] * 0.125f);
        val[c][r] = (col <= row) ? sv : -1e30f;
      }
    }
#pragma unroll
    for (int r = 0; r < 4; ++r) {
      float v0 = fmaxf(fmaxf(val[0][r], val[1][r]), fmaxf(val[2][r], val[3][r]));
#pragma unroll
      for (int off = 1; off < 16; off <<= 1) v0 = fmaxf(v0, __shfl_xor(v0, off, 64));
      float mn = fmaxf(m[r], v0);
      float alpha = __expf(m[r] - mn);
      m[r] = mn;
      float s = 0.f;
#pragma unroll
      for (int c = 0; c < 4; ++c) {
        float p = __expf(val[c][r] - mn);
        val[c][r] = p;
        s += p;
      }
#pragma unroll
      for (int off = 1; off < 16; off <<= 1) s += __shfl_xor(s, off, 64);
      l[r] = l[r] * alpha + s;
#pragma unroll
      for (int c = 0; c < 4; ++c) oacc[c][r] *= alpha;
    }
    // ---- P -> LDS (per-wave private, 144B row stride), re-fragment as A
#pragma unroll
    for (int c = 0; c < 4; ++c)
#pragma unroll
      for (int r = 0; r < 4; ++r)
        Pw[(g * 4 + r) * 72 + c * 16 + lq] = f2bf(val[c][r]);
    U8 pa0, pa1;
    pa0.u = *(const u16x8*)&Pw[lq * 72 + g * 8];
    pa1.u = *(const u16x8*)&Pw[lq * 72 + 32 + g * 8];
    // ---- PV: B = Vt rows (k-contig)
#pragma unroll
    for (int c = 0; c < 4; ++c) {
      const unsigned short* vp = &Vt[vbase + (size_t)(c * 16 + lq) * 2048 + kk0 + g * 8];
      U8 b0, b1;
      b0.u = *(const u16x8*)vp;
      b1.u = *(const u16x8*)(vp + 32);
      oacc[c] = __builtin_amdgcn_mfma_f32_16x16x32_bf16(pa0.b, b0.b, oacc[c], 0, 0, 0);
      oacc[c] = __builtin_amdgcn_mfma_f32_16x16x32_bf16(pa1.b, b1.b, oacc[c], 0, 0, 0);
    }
  }
  // ---- epilogue: O[b][s][h*64+dv]
#pragma unroll
  for (int c = 0; c < 4; ++c) {
    int col = h * 64 + c * 16 + lq;
#pragma unroll
    for (int r = 0; r < 4; ++r) {
      int srow = q0 + wid * 16 + g * 4 + r;
      O[((size_t)(b * 2048 + srow)) * 1024 + col] = f2bf(oacc[c][r] / l[r]);
    }
  }
}

// ---------------- launch ----------------
extern "C" void kernel_launch(void* const* d_in, const int* in_sizes, int n_in,
                              void* d_out, int out_size, void* d_ws, size_t ws_size,
                              hipStream_t stream) {
  const float* x  = (const float*)d_in[0];
  const float* Wq = (const float*)d_in[1];
  const float* bq = (const float*)d_in[2];
  const float* Wk = (const float*)d_in[3];
  const float* bk = (const float*)d_in[4];
  const float* Wv = (const float*)d_in[5];
  const float* bv = (const float*)d_in[6];
  const float* Wo = (const float*)d_in[7];
  const float* bo = (const float*)d_in[8];
  float* out = (float*)d_out;

  char* ws = (char*)d_ws;
  const size_t MB = 1024 * 1024;
  unsigned short* xb   = (unsigned short*)(ws + 0 * MB);   // 8 MB
  unsigned short* Wqt  = (unsigned short*)(ws + 8 * MB);   // 2 MB
  unsigned short* Wkt  = (unsigned short*)(ws + 10 * MB);  // 2 MB
  unsigned short* Wvt  = (unsigned short*)(ws + 12 * MB);  // 2 MB
  unsigned short* Wot  = (unsigned short*)(ws + 14 * MB);  // 2 MB
  unsigned short* Qws  = (unsigned short*)(ws + 16 * MB);  // 8 MB
  unsigned short* Kws  = (unsigned short*)(ws + 24 * MB);  // 8 MB
  unsigned short* Vtws = (unsigned short*)(ws + 32 * MB);  // 8 MB
  unsigned short* Ows  = (unsigned short*)(ws + 40 * MB);  // 8 MB

  k_conv_x<<<4096, 256, 0, stream>>>(x, xb);
  k_transpose<<<dim3(32, 32, 4), dim3(32, 8), 0, stream>>>(Wq, Wk, Wv, Wo,
                                                           Wqt, Wkt, Wvt, Wot);
  k_gemm_qkv<<<dim3(32, 8, 3), 256, 0, stream>>>(xb, Wqt, Wkt, Wvt, bq, bk, bv,
                                                 Qws, Kws, Vtws);
  k_flash<<<dim3(32, 16, 2), 256, 0, stream>>>(Qws, Kws, Vtws, Ows);
  k_gemm_out<<<dim3(32, 8), 256, 0, stream>>>(Ows, Wot, bo, out);
}